// Round 13
// baseline (541.121 us; speedup 1.0000x reference)
//
#include <hip/hip_runtime.h>
#include <hip/hip_bf16.h>
#include <math.h>

#define BT 2
#define SEQ 2048
#define DIM 1024
#define NH 16
#define HD 64
#define NTOK (BT*SEQ)          // 4096

typedef __attribute__((ext_vector_type(4))) float floatx4;
typedef __attribute__((ext_vector_type(8))) short shortx8;   // 8 bf16 = 4 VGPRs (MFMA frag)
typedef __attribute__((ext_vector_type(4))) short shortx4;

// async global->LDS, 16B per lane; dest is wave-uniform base + lane*16
#define GLL16(gp, lp) __builtin_amdgcn_global_load_lds( \
    (const __attribute__((address_space(1))) unsigned int*)(const void*)(gp), \
    (__attribute__((address_space(3))) unsigned int*)(void*)(lp), 16, 0, 0)

__device__ __forceinline__ float bf2f(unsigned short u) {
    unsigned int x = ((unsigned int)u) << 16;
    return __builtin_bit_cast(float, x);
}
__device__ __forceinline__ unsigned short f2bf(float f) {
    unsigned int x = __builtin_bit_cast(unsigned int, f);
    unsigned int lsb = (x >> 16) & 1u;
    x += 0x7fffu + lsb;
    return (unsigned short)(x >> 16);
}
// dual-dtype input read: isbf=1 -> bf16, else fp32 (validated: inputs are fp32)
__device__ __forceinline__ float ldin_f(const void* p, size_t i, int isbf) {
    return isbf ? bf2f(((const unsigned short*)p)[i]) : ((const float*)p)[i];
}

// ---------------- fused: input dtype detect + Householder Q (one block) ----------
__global__ __launch_bounds__(256) void prep_dh(const unsigned short* __restrict__ x,
                                               const void* __restrict__ vs,
                                               float* __restrict__ Qg,
                                               int* __restrict__ flagp) {
    __shared__ int cnt;
    __shared__ float vsh[64];
    int t = threadIdx.x;
    if (t == 0) cnt = 0;
    __syncthreads();
    unsigned short u = x[(size_t)t * 2];
    int e = (u >> 7) & 0xFF;
    if (e >= 100 && e <= 140) atomicAdd(&cnt, 1);
    __syncthreads();
    int isbf = (cnt >= 192) ? 1 : 0;
    if (t == 0) *flagp = isbf;
    // Householder: threads 0..63 own columns; barriers are block-uniform
    int j = t & 63;
    float Qc[64];
#pragma unroll
    for (int i = 0; i < 64; i++) Qc[i] = (i == j) ? 1.f : 0.f;
    for (int r = 0; r < 32; r++) {
        if (t < 64) vsh[j] = ldin_f(vs, r * 64 + j, isbf);
        __syncthreads();
        if (t < 64) {
            float va[64];
#pragma unroll
            for (int i = 0; i < 64; i++) va[i] = vsh[i];
            float vn0 = 0.f, vn1 = 0.f, vn2 = 0.f, vn3 = 0.f;
            float t0 = 0.f, t1 = 0.f, t2 = 0.f, t3 = 0.f;
#pragma unroll
            for (int i = 0; i < 16; i++) {
                vn0 += va[4 * i + 0] * va[4 * i + 0];
                vn1 += va[4 * i + 1] * va[4 * i + 1];
                vn2 += va[4 * i + 2] * va[4 * i + 2];
                vn3 += va[4 * i + 3] * va[4 * i + 3];
                t0 += va[4 * i + 0] * Qc[4 * i + 0];
                t1 += va[4 * i + 1] * Qc[4 * i + 1];
                t2 += va[4 * i + 2] * Qc[4 * i + 2];
                t3 += va[4 * i + 3] * Qc[4 * i + 3];
            }
            float vn = (vn0 + vn1) + (vn2 + vn3) + 1e-8f;
            float tt = (t0 + t1) + (t2 + t3);
            float c = (2.f / vn) * tt;
#pragma unroll
            for (int i = 0; i < 64; i++) Qc[i] -= c * va[i];
        }
        __syncthreads();
    }
    if (t < 64)
#pragma unroll
        for (int i = 0; i < 64; i++) Qg[i * 64 + j] = Qc[i];
}

// ---------------- fused: 5 weight transposes + rope table (one kernel) ----------
// blocks [0,3072): w_qkv  [3072,4096): w_out  [4096,5120): w_gate
// [5120,13312): w_mlp_g  [13312,17408): w_mlp_o  [17408,17664): rope table
__global__ __launch_bounds__(256) void prep_weights(
        const void* __restrict__ w_qkv, const void* __restrict__ w_out,
        const void* __restrict__ w_gate, const void* __restrict__ w_mlp_g,
        const void* __restrict__ w_mlp_o,
        unsigned short* __restrict__ wqkvT, unsigned short* __restrict__ woutT,
        unsigned short* __restrict__ wgateT, unsigned short* __restrict__ wmgT,
        unsigned short* __restrict__ wmoT,
        float* __restrict__ rtab, const int* __restrict__ flagp) {
    int id = blockIdx.x;
    if (id >= 17408) {                       // rope cos/sin table [2048][32] pairs
        int idx = (id - 17408) * 256 + threadIdx.x;   // s*32 + fi
        int s = idx >> 5, fi = idx & 31;
        float invf = __expf(-(float)fi * (9.210340371976184f / 32.f));
        float ang = (float)s * invf;
        rtab[2 * idx]     = cosf(ang);
        rtab[2 * idx + 1] = sinf(ang);
        return;
    }
    const void* in; unsigned short* out; int R, C, bx, by;
    if (id < 3072)       { in = w_qkv;   out = wqkvT;  R = 1024; C = 3072; int i2 = id;         bx = i2 % 96;  by = i2 / 96; }
    else if (id < 4096)  { in = w_out;   out = woutT;  R = 1024; C = 1024; int i2 = id - 3072;  bx = i2 % 32;  by = i2 / 32; }
    else if (id < 5120)  { in = w_gate;  out = wgateT; R = 1024; C = 1024; int i2 = id - 4096;  bx = i2 % 32;  by = i2 / 32; }
    else if (id < 13312) { in = w_mlp_g; out = wmgT;   R = 1024; C = 8192; int i2 = id - 5120;  bx = i2 % 256; by = i2 / 256; }
    else                 { in = w_mlp_o; out = wmoT;   R = 4096; C = 1024; int i2 = id - 13312; bx = i2 % 32;  by = i2 / 32; }
    int isbf = *flagp;
    __shared__ unsigned short tile[32][33];
    int c0 = bx * 32, r0 = by * 32;
    int tx = threadIdx.x & 31, ty = threadIdx.x >> 5;
#pragma unroll
    for (int i = 0; i < 4; i++) {
        size_t idx = (size_t)(r0 + ty + i * 8) * C + c0 + tx;
        tile[ty + i * 8][tx] = isbf ? ((const unsigned short*)in)[idx]
                                    : f2bf(((const float*)in)[idx]);
    }
    __syncthreads();
#pragma unroll
    for (int i = 0; i < 4; i++)
        out[(size_t)(c0 + ty + i * 8) * R + r0 + tx] = tile[tx][ty + i * 8];
}

// ---------------- pre-rotate q,k head-blocks of wqkvT by Q: W'[hb] = Q @ W[hb] ----
__global__ __launch_bounds__(256) void rotate_wqkv(unsigned short* __restrict__ wT,
                                                   const float* __restrict__ Qg) {
    __shared__ float Qs[64][64];
    __shared__ unsigned short tile[64][128];
    int bid = blockIdx.x;
    int row0 = (bid >> 3) * 64;      // head-block base row (0..2047)
    int col0 = (bid & 7) * 128;      // column chunk
    int t = threadIdx.x;
#pragma unroll
    for (int i = 0; i < 16; i++) {
        int idx = i * 256 + t;
        Qs[idx >> 6][idx & 63] = Qg[idx];
    }
#pragma unroll
    for (int i = 0; i < 8; i++) {
        int e = i * 256 + t;
        int r = e >> 5, cg = (e & 31) * 4;
        *(shortx4*)&tile[r][cg] = *(const shortx4*)&wT[(size_t)(row0 + r) * 1024 + col0 + cg];
    }
    __syncthreads();
    int ib = t >> 5;                 // 0..7
    int c = (t & 31) * 4;
    float acc[8][4];
#pragma unroll
    for (int rr = 0; rr < 8; rr++)
#pragma unroll
        for (int cx = 0; cx < 4; cx++) acc[rr][cx] = 0.f;
    for (int j = 0; j < 64; j++) {
        float t0 = bf2f(tile[j][c]);
        float t1 = bf2f(tile[j][c + 1]);
        float t2 = bf2f(tile[j][c + 2]);
        float t3 = bf2f(tile[j][c + 3]);
#pragma unroll
        for (int rr = 0; rr < 8; rr++) {
            float qv = Qs[rr * 8 + ib][j];
            acc[rr][0] += qv * t0;
            acc[rr][1] += qv * t1;
            acc[rr][2] += qv * t2;
            acc[rr][3] += qv * t3;
        }
    }
#pragma unroll
    for (int rr = 0; rr < 8; rr++) {
        int i = rr * 8 + ib;
        shortx4 o4;
#pragma unroll
        for (int cx = 0; cx < 4; cx++) o4[cx] = (short)f2bf(acc[rr][cx]);
        *(shortx4*)&wT[(size_t)(row0 + i) * 1024 + col0 + c] = o4;
    }
}

// ---------------- rmsnorm over D=1024, wave-shfl reduction (1 barrier) ----------
__global__ __launch_bounds__(256) void rmsnorm2(const void* __restrict__ x,
                                                unsigned short* __restrict__ h,
                                                const int* __restrict__ flagp) {
    int isbf = flagp ? *flagp : 1;
    __shared__ float wred[4];
    int row = blockIdx.x, t = threadIdx.x;
    size_t base = (size_t)row * DIM;
    float v[4];
    float ss = 0.f;
#pragma unroll
    for (int i = 0; i < 4; i++) {
        v[i] = ldin_f(x, base + t + 256 * i, isbf);
        ss += v[i] * v[i];
    }
#pragma unroll
    for (int m = 1; m < 64; m <<= 1) ss += __shfl_xor(ss, m, 64);
    if ((t & 63) == 0) wred[t >> 6] = ss;
    __syncthreads();
    float tot = (wred[0] + wred[1]) + (wred[2] + wred[3]);
    float rs = rsqrtf(tot * (1.f / 1024.f) + 1e-6f);
#pragma unroll
    for (int i = 0; i < 4; i++) h[base + t + 256 * i] = f2bf(v[i] * rs);
}

// ---------------- MFMA GEMM: BK=64, swizzled LDS, dbuf 2-phase, L2 super-blocks ---
// MODE: 0=bf16 store, 1=f32+resid, 2=gated combine x1=xin+resid*sigmoid(val+bias).
template<int MODE, int GM, int GN>
__global__ __launch_bounds__(256) void gemm_bt(const unsigned short* __restrict__ A,
                                               const unsigned short* __restrict__ Bt,
                                               void* __restrict__ C,
                                               const void* __restrict__ bias,
                                               const unsigned short* __restrict__ resid,
                                               const void* __restrict__ xin,
                                               const int* __restrict__ flagp,
                                               int M, int N, int K) {
    __shared__ __align__(16) unsigned short As[2][128][64];   // 32 KB
    __shared__ __align__(16) unsigned short Bs[2][64][64];    // 16 KB
    int isbf = flagp ? *flagp : 1;
    int t0 = (blockIdx.x & 7) * (gridDim.x >> 3) + (blockIdx.x >> 3);
    int nbn = N >> 6;
    constexpr int SB = GM * GN;
    int s0 = t0 / SB, inner = t0 % SB;
    int sbn = nbn / GN;
    int m0 = ((s0 / sbn) * GM + (inner % GM)) * 128;
    int n0 = ((s0 % sbn) * GN + (inner / GM)) * 64;
    int t = threadIdx.x;
    int lane = t & 63;
    int w = t >> 6;
    int wr = (w >> 1) * 64;
    int wc = (w & 1) * 32;
    int lr = lane & 15;
    int kg = lane >> 4;
    int l8 = lane >> 3, s8 = lane & 7;
    int segswz = (s8 ^ l8) * 8;              // global col offset (shorts), lane-const
    int cs0 = ((kg)     ^ (lr & 7)) * 8;     // LDS col (shorts), kk=0
    int cs1 = ((4 + kg) ^ (lr & 7)) * 8;     // kk=1

    floatx4 acc[4][2];
#pragma unroll
    for (int i = 0; i < 4; i++)
#pragma unroll
        for (int j = 0; j < 2; j++) acc[i][j] = (floatx4){0.f, 0.f, 0.f, 0.f};

    int rbase = w * 8 + l8;                  // staged row within 32-row group
    const unsigned short* aP0 = A + (size_t)(m0 + rbase +  0) * K + segswz;
    const unsigned short* aP1 = A + (size_t)(m0 + rbase + 32) * K + segswz;
    const unsigned short* aP2 = A + (size_t)(m0 + rbase + 64) * K + segswz;
    const unsigned short* aP3 = A + (size_t)(m0 + rbase + 96) * K + segswz;
    const unsigned short* bP0 = Bt + (size_t)(n0 + rbase +  0) * K + segswz;
    const unsigned short* bP1 = Bt + (size_t)(n0 + rbase + 32) * K + segswz;

    auto STAGE = [&](int s, int B) {
        int off = s * 64;
        GLL16(aP0 + off, &As[B][w * 8 +  0][0]);
        GLL16(aP1 + off, &As[B][w * 8 + 32][0]);
        GLL16(aP2 + off, &As[B][w * 8 + 64][0]);
        GLL16(aP3 + off, &As[B][w * 8 + 96][0]);
        GLL16(bP0 + off, &Bs[B][w * 8 +  0][0]);
        GLL16(bP1 + off, &Bs[B][w * 8 + 32][0]);
    };
    auto MM = [&](int B) {
        shortx8 af[4][2], bf[2][2];
#pragma unroll
        for (int i = 0; i < 4; i++) {
            af[i][0] = *(const shortx8*)&As[B][wr + i * 16 + lr][cs0];
            af[i][1] = *(const shortx8*)&As[B][wr + i * 16 + lr][cs1];
        }
#pragma unroll
        for (int j = 0; j < 2; j++) {
            bf[j][0] = *(const shortx8*)&Bs[B][wc + j * 16 + lr][cs0];
            bf[j][1] = *(const shortx8*)&Bs[B][wc + j * 16 + lr][cs1];
        }
#pragma unroll
        for (int i = 0; i < 4; i++)
#pragma unroll
            for (int j = 0; j < 2; j++) {
                acc[i][j] = __builtin_amdgcn_mfma_f32_16x16x32_bf16(af[i][0], bf[j][0], acc[i][j], 0, 0, 0);
                acc[i][j] = __builtin_amdgcn_mfma_f32_16x16x32_bf16(af[i][1], bf[j][1], acc[i][j], 0, 0, 0);
            }
    };

    int NS = K >> 6;                         // K multiple of 128 -> NS even
    STAGE(0, 0);
    __syncthreads();
    for (int s = 0; s < NS; s += 2) {
        if (s + 1 < NS) STAGE(s + 1, 1);     // prefetch hides under compute
        MM(0);
        __syncthreads();                     // vmcnt(0)+barrier: buf1 ready, buf0 free
        if (s + 1 < NS) {
            if (s + 2 < NS) STAGE(s + 2, 0);
            MM(1);
            __syncthreads();
        }
    }
#pragma unroll
    for (int i = 0; i < 4; i++) {
#pragma unroll
        for (int j = 0; j < 2; j++) {
            int col = n0 + wc + j * 16 + lr;
            int rb = m0 + wr + i * 16 + kg * 4;
            float bv = bias ? ldin_f(bias, col, isbf) : 0.f;
#pragma unroll
            for (int r = 0; r < 4; r++) {
                float val = acc[i][j][r] + bv;
                size_t oidx = (size_t)(rb + r) * N + col;
                if constexpr (MODE == 0) {
                    ((unsigned short*)C)[oidx] = f2bf(val);
                } else if constexpr (MODE == 1) {
                    ((float*)C)[oidx] = val + bf2f(resid[oidx]);
                } else {
                    float a = bf2f(resid[oidx]);               // ao
                    float sg = 1.f / (1.f + __expf(-val));
                    ((unsigned short*)C)[oidx] = f2bf(ldin_f(xin, oidx, isbf) + a * sg);
                }
            }
        }
    }
}

// ---------------- fused MLP-gate GEMM + GLU: act = val * gelu(g) ----------------
__global__ __launch_bounds__(256) void gemm_glu(const unsigned short* __restrict__ A,
                                                const unsigned short* __restrict__ Bt,
                                                unsigned short* __restrict__ act,
                                                const void* __restrict__ bias,
                                                const int* __restrict__ flagp) {
    __shared__ __align__(16) unsigned short As[2][128][64];   // 32 KB
    __shared__ __align__(16) unsigned short Bg[2][64][64];    // 16 KB
    __shared__ __align__(16) unsigned short Bv[2][64][64];    // 16 KB
    const int K = 1024;
    int isbf = *flagp;
    int t0 = (blockIdx.x & 7) * (gridDim.x >> 3) + (blockIdx.x >> 3);
    int s0 = t0 >> 6, inner = t0 & 63;
    int m0 = ((s0 >> 3) * 8 + (inner & 7)) * 128;
    int n0 = ((s0 & 7) * 8 + (inner >> 3)) * 64;
    int t = threadIdx.x;
    int lane = t & 63;
    int w = t >> 6;
    int wr = (w >> 1) * 64;
    int wc = (w & 1) * 32;
    int lr = lane & 15;
    int kg = lane >> 4;
    int l8 = lane >> 3, s8 = lane & 7;
    int segswz = (s8 ^ l8) * 8;
    int cs0 = ((kg)     ^ (lr & 7)) * 8;
    int cs1 = ((4 + kg) ^ (lr & 7)) * 8;

    floatx4 ag[4][2], av[4][2];
#pragma unroll
    for (int i = 0; i < 4; i++)
#pragma unroll
        for (int j = 0; j < 2; j++) {
            ag[i][j] = (floatx4){0.f, 0.f, 0.f, 0.f};
            av[i][j] = (floatx4){0.f, 0.f, 0.f, 0.f};
        }

    int rbase = w * 8 + l8;
    const unsigned short* aP0 = A + (size_t)(m0 + rbase +  0) * K + segswz;
    const unsigned short* aP1 = A + (size_t)(m0 + rbase + 32) * K + segswz;
    const unsigned short* aP2 = A + (size_t)(m0 + rbase + 64) * K + segswz;
    const unsigned short* aP3 = A + (size_t)(m0 + rbase + 96) * K + segswz;
    const unsigned short* gP0 = Bt + (size_t)(n0 + rbase +  0) * K + segswz;
    const unsigned short* gP1 = Bt + (size_t)(n0 + rbase + 32) * K + segswz;
    const unsigned short* vP0 = Bt + (size_t)(4096 + n0 + rbase +  0) * K + segswz;
    const unsigned short* vP1 = Bt + (size_t)(4096 + n0 + rbase + 32) * K + segswz;

    auto STAGE = [&](int s, int B) {
        int off = s * 64;
        GLL16(aP0 + off, &As[B][w * 8 +  0][0]);
        GLL16(aP1 + off, &As[B][w * 8 + 32][0]);
        GLL16(aP2 + off, &As[B][w * 8 + 64][0]);
        GLL16(aP3 + off, &As[B][w * 8 + 96][0]);
        GLL16(gP0 + off, &Bg[B][w * 8 +  0][0]);
        GLL16(gP1 + off, &Bg[B][w * 8 + 32][0]);
        GLL16(vP0 + off, &Bv[B][w * 8 +  0][0]);
        GLL16(vP1 + off, &Bv[B][w * 8 + 32][0]);
    };
    auto MM = [&](int B) {
        shortx8 af[4][2], gf[2][2], vf[2][2];
#pragma unroll
        for (int i = 0; i < 4; i++) {
            af[i][0] = *(const shortx8*)&As[B][wr + i * 16 + lr][cs0];
            af[i][1] = *(const shortx8*)&As[B][wr + i * 16 + lr][cs1];
        }
#pragma unroll
        for (int j = 0; j < 2; j++) {
            gf[j][0] = *(const shortx8*)&Bg[B][wc + j * 16 + lr][cs0];
            gf[j][1] = *(const shortx8*)&Bg[B][wc + j * 16 + lr][cs1];
            vf[j][0] = *(const shortx8*)&Bv[B][wc + j * 16 + lr][cs0];
            vf[j][1] = *(const shortx8*)&Bv[B][wc + j * 16 + lr][cs1];
        }
#pragma unroll
        for (int i = 0; i < 4; i++)
#pragma unroll
            for (int j = 0; j < 2; j++) {
                ag[i][j] = __builtin_amdgcn_mfma_f32_16x16x32_bf16(af[i][0], gf[j][0], ag[i][j], 0, 0, 0);
                ag[i][j] = __builtin_amdgcn_mfma_f32_16x16x32_bf16(af[i][1], gf[j][1], ag[i][j], 0, 0, 0);
                av[i][j] = __builtin_amdgcn_mfma_f32_16x16x32_bf16(af[i][0], vf[j][0], av[i][j], 0, 0, 0);
                av[i][j] = __builtin_amdgcn_mfma_f32_16x16x32_bf16(af[i][1], vf[j][1], av[i][j], 0, 0, 0);
            }
    };

    const int NS = K >> 6;                   // 16
    STAGE(0, 0);
    __syncthreads();
    for (int s = 0; s < NS; s += 2) {
        if (s + 1 < NS) STAGE(s + 1, 1);
        MM(0);
        __syncthreads();
        if (s + 1 < NS) {
            if (s + 2 < NS) STAGE(s + 2, 0);
            MM(1);
            __syncthreads();
        }
    }
#pragma unroll
    for (int i = 0; i < 4; i++) {
#pragma unroll
        for (int j = 0; j < 2; j++) {
            int col = n0 + wc + j * 16 + lr;
            int rb = m0 + wr + i * 16 + kg * 4;
            float bgv = ldin_f(bias, col, isbf);
            float bvv = ldin_f(bias, 4096 + col, isbf);
#pragma unroll
            for (int r = 0; r < 4; r++) {
                float g = ag[i][j][r] + bgv;
                float v = av[i][j][r] + bvv;
                float ge = 0.5f * g * (1.f + erff(g * 0.70710678118f));
                act[(size_t)(rb + r) * 4096 + col] = f2bf(v * ge);
            }
        }
    }
}

// ---------------- MFMA flash attention with FUSED RoPE (block-causal) ------------
// Reads q,k,v directly from qkv; rope applied in-register (Q) / at K-staging,
// using precomputed rtab. Math identical to former qk_rope3. Householder folded.
__global__ __launch_bounds__(512) void attn_mfma(const unsigned short* __restrict__ qkv,
                                                 const float* __restrict__ rtab,
                                                 unsigned short* __restrict__ attn) {
    __shared__ __align__(16) unsigned short Ks[64][72];      // [key][dim], +8 pad
    __shared__ __align__(16) unsigned short Vt[64 * 72];     // [dim][72], 8-key blocks XOR-swizzled
    __shared__ __align__(16) unsigned short Ps[8][16][72];   // per-wave P [qrow][key]
    int bid = blockIdx.x;
    int qblk = 15 - (bid & 15);                  // big q-blocks first
    int bh = bid >> 4;
    int b = bh >> 4, h = bh & 15;
    int tid = threadIdx.x;
    int wv = tid >> 6, lane = tid & 63;
    int l16 = lane & 15, quad = lane >> 4;
    int q0 = qblk * 128 + wv * 16;

    // Q load + in-register rope (aq0=dims<32, aq1=dims>=32 => rope pair per lane)
    const unsigned short* qrow = qkv + ((size_t)(b * SEQ + q0 + l16)) * 3072 + h * 64 + quad * 8;
    shortx8 aq0 = *(const shortx8*)(qrow);
    shortx8 aq1 = *(const shortx8*)(qrow + 32);
    {
        const float* qt = rtab + (size_t)(q0 + l16) * 64 + quad * 16;   // 8 (c,s) pairs
#pragma unroll
        for (int i = 0; i < 8; i++) {
            float cv = qt[2 * i], sv = qt[2 * i + 1];
            float ql = bf2f((unsigned short)aq0[i]);
            float qh = bf2f((unsigned short)aq1[i]);
            aq0[i] = (short)f2bf(ql * cv - qh * sv);
            aq1[i] = (short)f2bf(qh * cv + ql * sv);
        }
    }

    floatx4 o[4];
#pragma unroll
    for (int nt = 0; nt < 4; nt++) o[nt] = (floatx4){0.f, 0.f, 0.f, 0.f};
    float m_run = -1e30f, l_run = 0.f;           // this lane owns q-row q0+l16

    int nk = (qblk + 1) * 128;
    int skey = tid >> 3;              // 0..63
    int sd0 = (tid & 7) * 8;          // dim offset
    int sd0p = sd0 ^ 32;              // rope partner chunk
    const unsigned short* kb = qkv + ((size_t)(b * SEQ + skey)) * 3072 + 1024 + h * 64;
    const unsigned short* vbase = qkv + ((size_t)(b * SEQ + skey)) * 3072 + 2048 + h * 64 + sd0;
    int vco = (((skey >> 3) ^ (tid & 7)) * 8) + (skey & 7);
    float ksign = (sd0 < 32) ? -1.f : 1.f;

    shortx8 kvA = *(const shortx8*)(kb + sd0);    // prefetch tile 0 (both rope halves)
    shortx8 kvB = *(const shortx8*)(kb + sd0p);
    shortx8 vvv = *(const shortx8*)vbase;

    for (int k0 = 0; k0 < nk; k0 += 64) {
        __syncthreads();                          // prev tile's LDS reads done
        {   // K rope + store (fi = (sd0&31)+i; sign by half)
            const float* kt = rtab + (size_t)(k0 + skey) * 64 + (sd0 & 31) * 2;
            shortx8 ko;
#pragma unroll
            for (int i = 0; i < 8; i++) {
                float cv = kt[2 * i], sv = kt[2 * i + 1];
                float ka = bf2f((unsigned short)kvA[i]);
                float kp = bf2f((unsigned short)kvB[i]);
                ko[i] = (short)f2bf(ka * cv + ksign * kp * sv);
            }
            *(shortx8*)&Ks[skey][sd0] = ko;
        }
#pragma unroll
        for (int i = 0; i < 8; i++) Vt[(size_t)(sd0 + i) * 72 + vco] = (unsigned short)vvv[i];
        __syncthreads();                          // staged tile visible
        if (k0 + 64 < nk) {                       // prefetch next tile (hidden under compute)
            kvA = *(const shortx8*)(kb + (size_t)(k0 + 64) * 3072 + sd0);
            kvB = *(const shortx8*)(kb + (size_t)(k0 + 64) * 3072 + sd0p);
            vvv = *(const shortx8*)(vbase + (size_t)(k0 + 64) * 3072);
        }

        // swapped QK^T: D[key][q], col=l16=q-row, row=quad*4+r=key (within kt*16)
        floatx4 sc[4];
        __builtin_amdgcn_s_setprio(1);
#pragma unroll
        for (int kt = 0; kt < 4; kt++) {
            shortx8 bk0 = *(const shortx8*)&Ks[kt * 16 + l16][quad * 8];
            shortx8 bk1 = *(const shortx8*)&Ks[kt * 16 + l16][32 + quad * 8];
            floatx4 z = (floatx4){0.f, 0.f, 0.f, 0.f};
            z = __builtin_amdgcn_mfma_f32_16x16x32_bf16(bk0, aq0, z, 0, 0, 0);
            z = __builtin_amdgcn_mfma_f32_16x16x32_bf16(bk1, aq1, z, 0, 0, 0);
            sc[kt] = z;
        }
        __builtin_amdgcn_s_setprio(0);
        // lane holds 16 scores (keys kt*16+quad*4+r) for q-row l16
        float sv[16], mx[16];
#pragma unroll
        for (int kt = 0; kt < 4; kt++)
#pragma unroll
            for (int r = 0; r < 4; r++) sv[kt * 4 + r] = sc[kt][r] * 0.125f;
#pragma unroll
        for (int i = 0; i < 16; i++) mx[i] = sv[i];
#pragma unroll
        for (int st = 8; st > 0; st >>= 1)
#pragma unroll
            for (int i = 0; i < 8; i++)
                if (i < st) mx[i] = fmaxf(mx[i], mx[i + st]);
        float mt = mx[0];
        mt = fmaxf(mt, __shfl_xor(mt, 16, 64));   // reduce over 4 quads
        mt = fmaxf(mt, __shfl_xor(mt, 32, 64));
        float nm = fmaxf(m_run, mt);
        float al = __expf(m_run - nm);
        m_run = nm;
        float p[16];
#pragma unroll
        for (int i = 0; i < 16; i++) p[i] = __expf(sv[i] - nm);
        float sm[8];
#pragma unroll
        for (int i = 0; i < 8; i++) sm[i] = p[i] + p[i + 8];
        float ps = ((sm[0] + sm[1]) + (sm[2] + sm[3])) + ((sm[4] + sm[5]) + (sm[6] + sm[7]));
        ps += __shfl_xor(ps, 16, 64);
        ps += __shfl_xor(ps, 32, 64);
        l_run = l_run * al + ps;
        // P -> LDS as aligned b64 (keys kt*16+quad*4 .. +3 contiguous)
#pragma unroll
        for (int kt = 0; kt < 4; kt++) {
            shortx4 pk;
#pragma unroll
            for (int r = 0; r < 4; r++) pk[r] = (short)f2bf(p[kt * 4 + r]);
            *(shortx4*)&Ps[wv][l16][kt * 16 + quad * 4] = pk;
        }
        // rescale o: o-row quad*4+r needs al from lane l16=quad*4+r
#pragma unroll
        for (int r = 0; r < 4; r++) {
            float alr = __shfl(al, quad * 4 + r, 64);
            o[0][r] *= alr; o[1][r] *= alr; o[2][r] *= alr; o[3][r] *= alr;
        }
        // PV (wave-private Ps RAW: in-order, no barrier)
        __builtin_amdgcn_s_setprio(1);
#pragma unroll
        for (int h2 = 0; h2 < 2; h2++) {
            shortx8 ap = *(const shortx8*)&Ps[wv][l16][h2 * 32 + quad * 8];
#pragma unroll
            for (int nt = 0; nt < 4; nt++) {
                int dd = nt * 16 + l16;
                shortx8 bvv = *(const shortx8*)&Vt[(size_t)dd * 72 +
                                                   (((h2 * 4 + quad) ^ ((dd >> 3) & 7)) * 8)];
                o[nt] = __builtin_amdgcn_mfma_f32_16x16x32_bf16(ap, bvv, o[nt], 0, 0, 0);
            }
        }
        __builtin_amdgcn_s_setprio(0);
    }
#pragma unroll
    for (int r = 0; r < 4; r++) {
        float lv = __shfl(l_run, quad * 4 + r, 64);
        float inv_l = 1.f / lv;
        int s = q0 + quad * 4 + r;
        unsigned short* op = attn + ((size_t)(b * SEQ + s)) * DIM + h * 64;
#pragma unroll
        for (int nt = 0; nt < 4; nt++) op[nt * 16 + l16] = f2bf(o[nt][r] * inv_l);
    }
}

extern "C" void kernel_launch(void* const* d_in, const int* in_sizes, int n_in,
                              void* d_out, int out_size, void* d_ws, size_t ws_size,
                              hipStream_t stream) {
    const unsigned short* x        = (const unsigned short*)d_in[0];
    const void* vs       = d_in[3];
    const void* w_qkv    = d_in[4];
    const void* w_out    = d_in[5];
    const void* w_gate   = d_in[6];
    const void* b_gate   = d_in[7];
    const void* w_mlp_g  = d_in[8];
    const void* b_mlp_g  = d_in[9];
    const void* w_mlp_o  = d_in[10];
    const void* b_mlp_o  = d_in[11];
    float* out = (float*)d_out;    // reference output dtype is float32
    char* ws = (char*)d_ws;

    if (n_in < 12) return;
    if (in_sizes[0] != 4194304 || in_sizes[3] != 2048 || in_sizes[4] != 3145728 ||
        in_sizes[8] != 8388608 || in_sizes[10] != 4194304 || in_sizes[7] != 1024) return;

    const size_t o_T   = 0;            // transposed weights, 35,651,584
    const size_t o_Qg  = 35651584;     // Qg 16 KiB + flag (32 KiB reserved)
    const size_t o_h   = 35684352;     // 8,388,608
    const size_t o_B   = 44072960;     // 25,165,824: qkv (live through attn) | ao after attn
    const size_t o_C   = 69238784;     // attnb | x1, act after attn
    const size_t o_gv  = 94404608;     // rope table (512 KiB): live until attn done
    const size_t total = 161513472;
    if (ws_size < total) return;

    unsigned short* wqkvT  = (unsigned short*)(ws + o_T);             // [3072,1024]
    unsigned short* woutT  = (unsigned short*)(ws + o_T + 6291456);   // [1024,1024]
    unsigned short* wgateT = (unsigned short*)(ws + o_T + 8388608);   // [1024,1024]
    unsigned short* wmgT   = (unsigned short*)(ws + o_T + 10485760);  // [8192,1024]
    unsigned short* wmoT   = (unsigned short*)(ws + o_T + 27262976);  // [1024,4096]
    float*          Qg     = (float*)(ws + o_Qg);
    int*            flagp  = (int*)(ws + o_Qg + 16384);
    unsigned short* h      = (unsigned short*)(ws + o_h);
    unsigned short* qkv    = (unsigned short*)(ws + o_B);             // 24 MiB, live until attn done
    unsigned short* ao     = (unsigned short*)(ws + o_B + 8388608);   // written after attn
    unsigned short* attnb  = (unsigned short*)(ws + o_C + 16777216);
    unsigned short* x1     = (unsigned short*)(ws + o_C);             // after attn done
    unsigned short* act    = (unsigned short*)(ws + o_C + 8388608);   // 32 MiB, after attn done
    float*          rtab   = (float*)(ws + o_gv);                     // read through attn; act overlap is post-attn

    prep_dh<<<1, 256, 0, stream>>>(x, vs, Qg, flagp);
    prep_weights<<<17664, 256, 0, stream>>>(w_qkv, w_out, w_gate, w_mlp_g, w_mlp_o,
                                            wqkvT, woutT, wgateT, wmgT, wmoT, rtab, flagp);
    rotate_wqkv<<<256, 256, 0, stream>>>(wqkvT, Qg);   // fold q = (h Wq) Q^T into weights

    rmsnorm2<<<NTOK, 256, 0, stream>>>(x, h, flagp);
    gemm_bt<0, 4, 8><<<32 * 48, 256, 0, stream>>>(h, wqkvT, qkv, nullptr, nullptr, nullptr, flagp, NTOK, 3072, 1024);
    attn_mfma<<<BT * NH * (SEQ / 128), 512, 0, stream>>>(qkv, rtab, attnb);
    gemm_bt<0, 4, 8><<<32 * 16, 256, 0, stream>>>(attnb, woutT, ao, nullptr, nullptr, nullptr, flagp, NTOK, 1024, 1024);
    // gate GEMM fused with combine: x1 = x + ao * sigmoid(ao@Wg + bg)
    gemm_bt<2, 4, 8><<<32 * 16, 256, 0, stream>>>(ao, wgateT, x1, b_gate, ao, x, flagp, NTOK, 1024, 1024);
    rmsnorm2<<<NTOK, 256, 0, stream>>>(x1, h, nullptr);
    gemm_glu<<<32 * 64, 256, 0, stream>>>(h, wmgT, act, b_mlp_g, flagp);
    gemm_bt<1, 2, 4><<<32 * 16, 256, 0, stream>>>(act, wmoT, (void*)out, b_mlp_o, x1, nullptr, flagp, NTOK, 1024, 4096);
}